// Round 6
// baseline (230.443 us; speedup 1.0000x reference)
//
#include <hip/hip_runtime.h>
#include <hip/hip_bf16.h>

#define N_NODES 100000
#define R_REL 4
#define E_EDGES 160000
#define D 128
#define NEG_SLOPE 0.2f
#define CAP 48   // max edges per dst (all relations); Poisson(6.4) => P(deg>48) ~ 1e-25/node

typedef unsigned short u16x8 __attribute__((ext_vector_type(8)));
typedef unsigned short u16x4 __attribute__((ext_vector_type(4)));
typedef __bf16 bf16x8v __attribute__((ext_vector_type(8)));
typedef float f32x4 __attribute__((ext_vector_type(4)));

__device__ inline unsigned short f2bf(float f) {
    unsigned u = __float_as_uint(f);
    return (unsigned short)((u + 0x7FFFu + ((u >> 16) & 1u)) >> 16);
}
__device__ inline float bf2f(unsigned short h) {
    return __uint_as_float(((unsigned)h) << 16);
}

// wl[r,d] = sum_e W_src[r,d,e]*attn_l[r,e]; wr likewise; btot = sum_r gat_bias + h_bias
__global__ void k_prep(const float* __restrict__ Wsrc, const float* __restrict__ Wdst,
                       const float* __restrict__ al, const float* __restrict__ ar,
                       const float* __restrict__ gb, const float* __restrict__ hb,
                       float* __restrict__ wl, float* __restrict__ wr, float* __restrict__ btot) {
    int t = threadIdx.x;            // 512 threads
    int r = t >> 7, d = t & 127;
    const float* as = al + r * D;
    const float* ad = ar + r * D;
    const float* rs = Wsrc + (r * D + d) * D;
    const float* rd = Wdst + (r * D + d) * D;
    float s0 = 0.f, s1 = 0.f;
    for (int e = 0; e < D; e++) { s0 += rs[e] * as[e]; s1 += rd[e] * ad[e]; }
    wl[r * D + d] = s0; wr[r * D + d] = s1;
    if (t < D) {
        float b = hb[t];
        for (int r2 = 0; r2 < R_REL; r2++) b += gb[r2 * D + t];
        btot[t] = b;
    }
}

// Wt[r][e][k] = bf16(W_src[r][k][e])
__global__ void k_transw(const float* __restrict__ Wsrc, unsigned short* __restrict__ Wt) {
    int idx = blockIdx.x * 256 + threadIdx.x;
    if (idx >= R_REL * D * D) return;
    int r = idx >> 14; int rem = idx & 16383; int e = rem >> 7; int k = rem & 127;
    Wt[idx] = f2bf(Wsrc[(r * D + k) * D + e]);
}

// fused: coalesced read of x (wave covers 2 rows), emits xb (bf16 cast),
// el[r,n] = x[n]·wl[r], er[r,n] = x[n]·wr[r] via shuffle reduce
__global__ __launch_bounds__(256) void k_scores_cast(const float* __restrict__ x,
        const float* __restrict__ wl, const float* __restrict__ wr,
        unsigned short* __restrict__ xb, float* __restrict__ el, float* __restrict__ er) {
    __shared__ float swl[R_REL * D], swr[R_REL * D];
    int t = threadIdx.x;
    for (int i = t; i < R_REL * D; i += 256) { swl[i] = wl[i]; swr[i] = wr[i]; }
    __syncthreads();
    int wv = t >> 6, lane = t & 63;
    int half = lane >> 5, q = lane & 31;           // q: float4 index within row
    long n = (long)blockIdx.x * 8 + wv * 2 + half; // N divisible by 8 -> no tail
    float4 v = ((const float4*)(x + n * D))[q];
    u16x4 ov;
    ov[0] = f2bf(v.x); ov[1] = f2bf(v.y); ov[2] = f2bf(v.z); ov[3] = f2bf(v.w);
    *(u16x4*)(xb + n * D + q * 4) = ov;
    float accl[R_REL], accr[R_REL];
    #pragma unroll
    for (int r = 0; r < R_REL; r++) {
        float4 w = ((const float4*)(swl + r * D))[q];
        accl[r] = v.x * w.x + v.y * w.y + v.z * w.z + v.w * w.w;
        float4 u = ((const float4*)(swr + r * D))[q];
        accr[r] = v.x * u.x + v.y * u.y + v.z * u.z + v.w * u.w;
    }
    #pragma unroll
    for (int r = 0; r < R_REL; r++) {
        #pragma unroll
        for (int d = 16; d >= 1; d >>= 1) {
            accl[r] += __shfl_xor(accl[r], d);
            accr[r] += __shfl_xor(accr[r], d);
        }
    }
    if (q == 0) {
        #pragma unroll
        for (int r = 0; r < R_REL; r++) {
            el[r * N_NODES + n] = accl[r];
            er[r * N_NODES + n] = accr[r];
        }
    }
}

// hs[r][n][e] bf16 = x_bf16 @ W_src[r] via mfma_f32_16x16x32_bf16.
// LDS-free: weight fragments loaded straight from global (64 KB total, L1/L2
// resident; all 4 waves of a block walk the same W_r). No barriers, no bank
// conflicts, no staging stores (round-5 profile: 1.6M conflicts, 2 syncs/rel).
__global__ __launch_bounds__(256) void k_gemm(const unsigned short* __restrict__ xb,
                                              const unsigned short* __restrict__ Wt,
                                              unsigned short* __restrict__ hs) {
    int tid = threadIdx.x;
    int w = tid >> 6, l = tid & 63;
    int row16 = l & 15, kgrp = l >> 4;
    int n0 = blockIdx.x * 128;
    bf16x8v a[2][4];
    int nr[2];
    #pragma unroll
    for (int rf = 0; rf < 2; rf++) {
        int nrow = n0 + w * 32 + rf * 16 + row16;
        nr[rf] = nrow;
        int nc = nrow < N_NODES ? nrow : N_NODES - 1;
        #pragma unroll
        for (int kf = 0; kf < 4; kf++)
            a[rf][kf] = *(const bf16x8v*)(xb + (long)nc * D + kf * 32 + kgrp * 8);
    }
    for (int r = 0; r < R_REL; r++) {
        const unsigned short* Wr = Wt + r * D * D + row16 * D + kgrp * 8;
        f32x4 acc[2][8];
        #pragma unroll
        for (int rf = 0; rf < 2; rf++)
            #pragma unroll
            for (int et = 0; et < 8; et++) {
                acc[rf][et][0] = 0.f; acc[rf][et][1] = 0.f;
                acc[rf][et][2] = 0.f; acc[rf][et][3] = 0.f;
            }
        #pragma unroll
        for (int kf = 0; kf < 4; kf++) {
            #pragma unroll
            for (int et = 0; et < 8; et++) {
                // lane (row16,kgrp): W^T row et*16+row16, k-cols kf*32+kgrp*8..+8
                bf16x8v wf = *(const bf16x8v*)(Wr + et * 16 * D + kf * 32);
                acc[0][et] = __builtin_amdgcn_mfma_f32_16x16x32_bf16(wf, a[0][kf], acc[0][et], 0, 0, 0);
                acc[1][et] = __builtin_amdgcn_mfma_f32_16x16x32_bf16(wf, a[1][kf], acc[1][et], 0, 0, 0);
            }
        }
        #pragma unroll
        for (int rf = 0; rf < 2; rf++) {
            if (nr[rf] < N_NODES) {
                unsigned short* orow = hs + ((long)r * N_NODES + nr[rf]) * D;
                #pragma unroll
                for (int et = 0; et < 8; et++) {
                    u16x4 o;
                    o[0] = f2bf(acc[rf][et][0]); o[1] = f2bf(acc[rf][et][1]);
                    o[2] = f2bf(acc[rf][et][2]); o[3] = f2bf(acc[rf][et][3]);
                    *(u16x4*)(orow + et * 16 + kgrp * 4) = o;
                }
            }
        }
    }
}

// single per-edge pass: one atomic, scatter rowid into dst bucket
__global__ void k_scatter(const int* __restrict__ esrc, const int* __restrict__ edst,
                          unsigned* __restrict__ cnt, int* __restrict__ eidx) {
    int e = blockIdx.x * 256 + threadIdx.x;
    if (e >= E_EDGES) return;
    int r = blockIdx.y;
    int t = r * E_EDGES + e;
    int src = esrc[t], dst = edst[t];
    unsigned pos = atomicAdd(cnt + dst, 1u);
    if (pos < CAP) eidx[dst * CAP + pos] = r * N_NODES + src;
}

// one wave per dst: in-wave softmax over its <=48 edges, then 4-slot gather-accumulate
__global__ __launch_bounds__(256) void k_agg(const int* __restrict__ eidx,
                                             const unsigned* __restrict__ cnt,
                                             const float* __restrict__ el,
                                             const float* __restrict__ er,
                                             const unsigned short* __restrict__ hs,
                                             const float* __restrict__ btot,
                                             float* __restrict__ out) {
    int wv = threadIdx.x >> 6, lane = threadIdx.x & 63;
    int dst = blockIdx.x * 4 + wv;
    if (dst >= N_NODES) return;
    unsigned num = cnt[dst];
    if (num > CAP) num = CAP;
    int rowid = 0, r = 0;
    float p = 0.f;
    if (lane < num) {
        rowid = eidx[dst * CAP + lane];          // rowid = r*N + src
        r = (int)((unsigned)rowid / (unsigned)N_NODES);
        float lg = el[rowid] + er[r * N_NODES + dst];
        lg = lg > 0.f ? lg : NEG_SLOPE * lg;
        p = __expf(lg);
    }
    // per-relation denominators via wave reduction (full EXEC here)
    float denom[R_REL];
    #pragma unroll
    for (int rr = 0; rr < R_REL; rr++) {
        float v = (r == rr) ? p : 0.f;
        #pragma unroll
        for (int d = 1; d < 64; d <<= 1) v += __shfl_xor(v, d);
        denom[rr] = v;
    }
    float alpha = (lane < num) ? p / denom[r] : 0.f;
    // gather-accumulate: 4 slots x 16 lanes (16B per lane covers a 256B hs row).
    // UNIFORM trip count: every lane executes every __shfl at full EXEC
    // (shfl from an exited lane is undefined on CDNA — round-3/4 bug).
    int slot = lane >> 4, c16 = lane & 15;
    float acc[8] = {0.f, 0.f, 0.f, 0.f, 0.f, 0.f, 0.f, 0.f};
    unsigned iters = (num + 3) >> 2;
    for (unsigned i = 0; i < iters; i++) {
        unsigned q = slot + i * 4;
        int rid = __shfl(rowid, (int)q);
        float al = __shfl(alpha, (int)q);
        if (q < num) {
            u16x8 v = *(const u16x8*)(hs + (long)rid * D + c16 * 8);
            #pragma unroll
            for (int j = 0; j < 8; j++) acc[j] += al * bf2f(v[j]);
        }
    }
    #pragma unroll
    for (int j = 0; j < 8; j++) {
        acc[j] += __shfl_xor(acc[j], 16);
        acc[j] += __shfl_xor(acc[j], 32);
    }
    if (slot == 0) {
        const float4 b0 = *(const float4*)(btot + c16 * 8);
        const float4 b1 = *(const float4*)(btot + c16 * 8 + 4);
        float4 o0, o1;
        o0.x = acc[0] + b0.x; o0.y = acc[1] + b0.y; o0.z = acc[2] + b0.z; o0.w = acc[3] + b0.w;
        o1.x = acc[4] + b1.x; o1.y = acc[5] + b1.y; o1.z = acc[6] + b1.z; o1.w = acc[7] + b1.w;
        o0.x = o0.x > 0.f ? o0.x : 0.f; o0.y = o0.y > 0.f ? o0.y : 0.f;
        o0.z = o0.z > 0.f ? o0.z : 0.f; o0.w = o0.w > 0.f ? o0.w : 0.f;
        o1.x = o1.x > 0.f ? o1.x : 0.f; o1.y = o1.y > 0.f ? o1.y : 0.f;
        o1.z = o1.z > 0.f ? o1.z : 0.f; o1.w = o1.w > 0.f ? o1.w : 0.f;
        *(float4*)(out + (long)dst * D + c16 * 8) = o0;
        *(float4*)(out + (long)dst * D + c16 * 8 + 4) = o1;
    }
}

extern "C" void kernel_launch(void* const* d_in, const int* in_sizes, int n_in,
                              void* d_out, int out_size, void* d_ws, size_t ws_size,
                              hipStream_t stream) {
    const float* x    = (const float*)d_in[0];
    const int*   esrc = (const int*)d_in[1];
    const int*   edst = (const int*)d_in[2];
    const float* Wsrc = (const float*)d_in[3];
    const float* Wdst = (const float*)d_in[4];
    const float* al   = (const float*)d_in[5];
    const float* ar   = (const float*)d_in[6];
    const float* gb   = (const float*)d_in[7];
    const float* hb   = (const float*)d_in[8];
    float* out = (float*)d_out;

    char* ws = (char*)d_ws;
    size_t o = 0;
    auto alloc = [&](size_t bytes) -> char* {
        char* r = ws + o; o += (bytes + 255) & ~(size_t)255; return r;
    };
    unsigned short* xb  = (unsigned short*)alloc((size_t)N_NODES * D * 2);   // 25.6 MB
    unsigned short* hsb = (unsigned short*)alloc((size_t)R_REL * N_NODES * D * 2);
    unsigned short* Wt  = (unsigned short*)alloc((size_t)R_REL * D * D * 2);
    float* el   = (float*)alloc((size_t)R_REL * N_NODES * 4);
    float* er   = (float*)alloc((size_t)R_REL * N_NODES * 4);
    float* wl   = (float*)alloc(R_REL * D * 4);
    float* wr   = (float*)alloc(R_REL * D * 4);
    float* btot = (float*)alloc(D * 4);
    unsigned* cnt = (unsigned*)alloc((size_t)N_NODES * 4);
    // eidx (19.2 MB) aliases xb (25.6 MB): xb is dead after k_gemm, and
    // k_scatter/k_agg are stream-ordered after k_gemm.
    int* eidx = (int*)xb;

    hipMemsetAsync(cnt, 0, (size_t)N_NODES * 4, stream);
    k_prep<<<dim3(1), dim3(512), 0, stream>>>(Wsrc, Wdst, al, ar, gb, hb, wl, wr, btot);
    k_transw<<<dim3((R_REL * D * D + 255) / 256), dim3(256), 0, stream>>>(Wsrc, Wt);
    k_scores_cast<<<dim3(N_NODES / 8), dim3(256), 0, stream>>>(x, wl, wr, xb, el, er);
    k_gemm<<<dim3((N_NODES + 127) / 128), dim3(256), 0, stream>>>(xb, Wt, hsb);
    k_scatter<<<dim3((E_EDGES + 255) / 256, R_REL), dim3(256), 0, stream>>>(esrc, edst, cnt, eidx);
    k_agg<<<dim3((N_NODES + 3) / 4), dim3(256), 0, stream>>>(eidx, cnt, el, er, hsb, btot, out);
}

// Round 7
// 199.408 us; speedup vs baseline: 1.1556x; 1.1556x over previous
//
#include <hip/hip_runtime.h>
#include <hip/hip_bf16.h>

#define N_NODES 100000
#define R_REL 4
#define E_EDGES 160000
#define D 128
#define NEG_SLOPE 0.2f
#define CAP 48   // max edges per dst (all relations); Poisson(6.4) => P(deg>48) ~ 1e-25/node

typedef unsigned short u16x8 __attribute__((ext_vector_type(8)));
typedef unsigned short u16x4 __attribute__((ext_vector_type(4)));
typedef __bf16 bf16x8v __attribute__((ext_vector_type(8)));
typedef float f32x4 __attribute__((ext_vector_type(4)));

__device__ inline unsigned short f2bf(float f) {
    unsigned u = __float_as_uint(f);
    return (unsigned short)((u + 0x7FFFu + ((u >> 16) & 1u)) >> 16);
}
__device__ inline float bf2f(unsigned short h) {
    return __uint_as_float(((unsigned)h) << 16);
}

// wl[r,d] = sum_e W_src[r,d,e]*attn_l[r,e]; wr likewise; btot = sum_r gat_bias + h_bias
__global__ void k_prep(const float* __restrict__ Wsrc, const float* __restrict__ Wdst,
                       const float* __restrict__ al, const float* __restrict__ ar,
                       const float* __restrict__ gb, const float* __restrict__ hb,
                       float* __restrict__ wl, float* __restrict__ wr, float* __restrict__ btot) {
    int t = threadIdx.x;            // 512 threads
    int r = t >> 7, d = t & 127;
    const float* as = al + r * D;
    const float* ad = ar + r * D;
    const float* rs = Wsrc + (r * D + d) * D;
    const float* rd = Wdst + (r * D + d) * D;
    float s0 = 0.f, s1 = 0.f;
    for (int e = 0; e < D; e++) { s0 += rs[e] * as[e]; s1 += rd[e] * ad[e]; }
    wl[r * D + d] = s0; wr[r * D + d] = s1;
    if (t < D) {
        float b = hb[t];
        for (int r2 = 0; r2 < R_REL; r2++) b += gb[r2 * D + t];
        btot[t] = b;
    }
}

// Wt[r][e][k] = bf16(W_src[r][k][e])
__global__ void k_transw(const float* __restrict__ Wsrc, unsigned short* __restrict__ Wt) {
    int idx = blockIdx.x * 256 + threadIdx.x;
    if (idx >= R_REL * D * D) return;
    int r = idx >> 14; int rem = idx & 16383; int e = rem >> 7; int k = rem & 127;
    Wt[idx] = f2bf(Wsrc[(r * D + k) * D + e]);
}

// fused: coalesced read of x (wave covers 2 rows), emits xb (bf16 cast),
// el[r,n] = x[n]·wl[r], er[r,n] = x[n]·wr[r] via shuffle reduce
__global__ __launch_bounds__(256) void k_scores_cast(const float* __restrict__ x,
        const float* __restrict__ wl, const float* __restrict__ wr,
        unsigned short* __restrict__ xb, float* __restrict__ el, float* __restrict__ er) {
    __shared__ float swl[R_REL * D], swr[R_REL * D];
    int t = threadIdx.x;
    for (int i = t; i < R_REL * D; i += 256) { swl[i] = wl[i]; swr[i] = wr[i]; }
    __syncthreads();
    int wv = t >> 6, lane = t & 63;
    int half = lane >> 5, q = lane & 31;           // q: float4 index within row
    long n = (long)blockIdx.x * 8 + wv * 2 + half; // N divisible by 8 -> no tail
    float4 v = ((const float4*)(x + n * D))[q];
    u16x4 ov;
    ov[0] = f2bf(v.x); ov[1] = f2bf(v.y); ov[2] = f2bf(v.z); ov[3] = f2bf(v.w);
    *(u16x4*)(xb + n * D + q * 4) = ov;
    float accl[R_REL], accr[R_REL];
    #pragma unroll
    for (int r = 0; r < R_REL; r++) {
        float4 w = ((const float4*)(swl + r * D))[q];
        accl[r] = v.x * w.x + v.y * w.y + v.z * w.z + v.w * w.w;
        float4 u = ((const float4*)(swr + r * D))[q];
        accr[r] = v.x * u.x + v.y * u.y + v.z * u.z + v.w * u.w;
    }
    #pragma unroll
    for (int r = 0; r < R_REL; r++) {
        #pragma unroll
        for (int d = 16; d >= 1; d >>= 1) {
            accl[r] += __shfl_xor(accl[r], d);
            accr[r] += __shfl_xor(accr[r], d);
        }
    }
    if (q == 0) {
        #pragma unroll
        for (int r = 0; r < R_REL; r++) {
            el[r * N_NODES + n] = accl[r];
            er[r * N_NODES + n] = accr[r];
        }
    }
}

// hs[r][n][e] bf16 = x_bf16 @ W_src[r] via mfma_f32_16x16x32_bf16.
// One relation per blockIdx.y: stage W_r into LDS ONCE per block (r5 staged it
// 4x with 8 barriers -> serial overhead), 256 rows x 8 waves, 1 barrier total.
__global__ __launch_bounds__(512) void k_gemm(const unsigned short* __restrict__ xb,
                                              const unsigned short* __restrict__ Wt,
                                              unsigned short* __restrict__ hs) {
    __shared__ unsigned short B[D][D + 8];   // padded: 128 x 136 bf16
    int tid = threadIdx.x;
    int w = tid >> 6, l = tid & 63;
    int row16 = l & 15, kgrp = l >> 4;
    int r = blockIdx.y;
    int n0 = blockIdx.x * 256;
    // hoist A-fragments (global reads overlap the LDS staging below)
    bf16x8v a[2][4];
    int nr[2];
    #pragma unroll
    for (int rf = 0; rf < 2; rf++) {
        int nrow = n0 + w * 32 + rf * 16 + row16;
        nr[rf] = nrow;
        int nc = nrow < N_NODES ? nrow : N_NODES - 1;
        #pragma unroll
        for (int kf = 0; kf < 4; kf++)
            a[rf][kf] = *(const bf16x8v*)(xb + (long)nc * D + kf * 32 + kgrp * 8);
    }
    // stage W_r: 512 threads x 4 iters x 8 elems = 16384
    const unsigned short* Wr = Wt + r * D * D;
    #pragma unroll
    for (int it = 0; it < 4; it++) {
        int fi = (it * 512 + tid) * 8;
        *(u16x8*)(&B[fi >> 7][fi & 127]) = *(const u16x8*)(Wr + fi);
    }
    __syncthreads();
    f32x4 acc[2][8];
    #pragma unroll
    for (int rf = 0; rf < 2; rf++)
        #pragma unroll
        for (int et = 0; et < 8; et++) {
            acc[rf][et][0] = 0.f; acc[rf][et][1] = 0.f;
            acc[rf][et][2] = 0.f; acc[rf][et][3] = 0.f;
        }
    #pragma unroll
    for (int kf = 0; kf < 4; kf++) {
        #pragma unroll
        for (int et = 0; et < 8; et++) {
            bf16x8v av = *(const bf16x8v*)(&B[et * 16 + row16][kf * 32 + kgrp * 8]);
            acc[0][et] = __builtin_amdgcn_mfma_f32_16x16x32_bf16(av, a[0][kf], acc[0][et], 0, 0, 0);
            acc[1][et] = __builtin_amdgcn_mfma_f32_16x16x32_bf16(av, a[1][kf], acc[1][et], 0, 0, 0);
        }
    }
    #pragma unroll
    for (int rf = 0; rf < 2; rf++) {
        if (nr[rf] < N_NODES) {
            unsigned short* orow = hs + ((long)r * N_NODES + nr[rf]) * D;
            #pragma unroll
            for (int et = 0; et < 8; et++) {
                u16x4 o;
                o[0] = f2bf(acc[rf][et][0]); o[1] = f2bf(acc[rf][et][1]);
                o[2] = f2bf(acc[rf][et][2]); o[3] = f2bf(acc[rf][et][3]);
                *(u16x4*)(orow + et * 16 + kgrp * 4) = o;
            }
        }
    }
}

// single per-edge pass: one atomic, scatter rowid into dst bucket
__global__ void k_scatter(const int* __restrict__ esrc, const int* __restrict__ edst,
                          unsigned* __restrict__ cnt, int* __restrict__ eidx) {
    int e = blockIdx.x * 256 + threadIdx.x;
    if (e >= E_EDGES) return;
    int r = blockIdx.y;
    int t = r * E_EDGES + e;
    int src = esrc[t], dst = edst[t];
    unsigned pos = atomicAdd(cnt + dst, 1u);
    if (pos < CAP) eidx[dst * CAP + pos] = r * N_NODES + src;
}

// one wave per dst: in-wave softmax over its <=48 edges, then 4-slot gather-accumulate
__global__ __launch_bounds__(256) void k_agg(const int* __restrict__ eidx,
                                             const unsigned* __restrict__ cnt,
                                             const float* __restrict__ el,
                                             const float* __restrict__ er,
                                             const unsigned short* __restrict__ hs,
                                             const float* __restrict__ btot,
                                             float* __restrict__ out) {
    int wv = threadIdx.x >> 6, lane = threadIdx.x & 63;
    int dst = blockIdx.x * 4 + wv;
    if (dst >= N_NODES) return;
    unsigned num = cnt[dst];
    if (num > CAP) num = CAP;
    int rowid = 0, r = 0;
    float p = 0.f;
    if (lane < num) {
        rowid = eidx[dst * CAP + lane];          // rowid = r*N + src
        r = (int)((unsigned)rowid / (unsigned)N_NODES);
        float lg = el[rowid] + er[r * N_NODES + dst];
        lg = lg > 0.f ? lg : NEG_SLOPE * lg;
        p = __expf(lg);
    }
    // per-relation denominators via wave reduction (full EXEC here)
    float denom[R_REL];
    #pragma unroll
    for (int rr = 0; rr < R_REL; rr++) {
        float v = (r == rr) ? p : 0.f;
        #pragma unroll
        for (int d = 1; d < 64; d <<= 1) v += __shfl_xor(v, d);
        denom[rr] = v;
    }
    float alpha = (lane < num) ? p / denom[r] : 0.f;
    // gather-accumulate: 4 slots x 16 lanes (16B per lane covers a 256B hs row).
    // UNIFORM trip count: every lane executes every __shfl at full EXEC
    // (shfl from an exited lane is undefined on CDNA — round-3/4 bug).
    int slot = lane >> 4, c16 = lane & 15;
    float acc[8] = {0.f, 0.f, 0.f, 0.f, 0.f, 0.f, 0.f, 0.f};
    unsigned iters = (num + 3) >> 2;
    for (unsigned i = 0; i < iters; i++) {
        unsigned q = slot + i * 4;
        int rid = __shfl(rowid, (int)q);
        float al = __shfl(alpha, (int)q);
        if (q < num) {
            u16x8 v = *(const u16x8*)(hs + (long)rid * D + c16 * 8);
            #pragma unroll
            for (int j = 0; j < 8; j++) acc[j] += al * bf2f(v[j]);
        }
    }
    #pragma unroll
    for (int j = 0; j < 8; j++) {
        acc[j] += __shfl_xor(acc[j], 16);
        acc[j] += __shfl_xor(acc[j], 32);
    }
    if (slot == 0) {
        const float4 b0 = *(const float4*)(btot + c16 * 8);
        const float4 b1 = *(const float4*)(btot + c16 * 8 + 4);
        float4 o0, o1;
        o0.x = acc[0] + b0.x; o0.y = acc[1] + b0.y; o0.z = acc[2] + b0.z; o0.w = acc[3] + b0.w;
        o1.x = acc[4] + b1.x; o1.y = acc[5] + b1.y; o1.z = acc[6] + b1.z; o1.w = acc[7] + b1.w;
        o0.x = o0.x > 0.f ? o0.x : 0.f; o0.y = o0.y > 0.f ? o0.y : 0.f;
        o0.z = o0.z > 0.f ? o0.z : 0.f; o0.w = o0.w > 0.f ? o0.w : 0.f;
        o1.x = o1.x > 0.f ? o1.x : 0.f; o1.y = o1.y > 0.f ? o1.y : 0.f;
        o1.z = o1.z > 0.f ? o1.z : 0.f; o1.w = o1.w > 0.f ? o1.w : 0.f;
        *(float4*)(out + (long)dst * D + c16 * 8) = o0;
        *(float4*)(out + (long)dst * D + c16 * 8 + 4) = o1;
    }
}

extern "C" void kernel_launch(void* const* d_in, const int* in_sizes, int n_in,
                              void* d_out, int out_size, void* d_ws, size_t ws_size,
                              hipStream_t stream) {
    const float* x    = (const float*)d_in[0];
    const int*   esrc = (const int*)d_in[1];
    const int*   edst = (const int*)d_in[2];
    const float* Wsrc = (const float*)d_in[3];
    const float* Wdst = (const float*)d_in[4];
    const float* al   = (const float*)d_in[5];
    const float* ar   = (const float*)d_in[6];
    const float* gb   = (const float*)d_in[7];
    const float* hb   = (const float*)d_in[8];
    float* out = (float*)d_out;

    char* ws = (char*)d_ws;
    size_t o = 0;
    auto alloc = [&](size_t bytes) -> char* {
        char* r = ws + o; o += (bytes + 255) & ~(size_t)255; return r;
    };
    unsigned short* xb  = (unsigned short*)alloc((size_t)N_NODES * D * 2);   // 25.6 MB
    unsigned short* hsb = (unsigned short*)alloc((size_t)R_REL * N_NODES * D * 2);
    unsigned short* Wt  = (unsigned short*)alloc((size_t)R_REL * D * D * 2);
    float* el   = (float*)alloc((size_t)R_REL * N_NODES * 4);
    float* er   = (float*)alloc((size_t)R_REL * N_NODES * 4);
    float* wl   = (float*)alloc(R_REL * D * 4);
    float* wr   = (float*)alloc(R_REL * D * 4);
    float* btot = (float*)alloc(D * 4);
    unsigned* cnt = (unsigned*)alloc((size_t)N_NODES * 4);
    // eidx (19.2 MB) aliases xb (25.6 MB): xb is dead after k_gemm, and
    // k_scatter/k_agg are stream-ordered after k_gemm.
    int* eidx = (int*)xb;

    hipMemsetAsync(cnt, 0, (size_t)N_NODES * 4, stream);
    k_prep<<<dim3(1), dim3(512), 0, stream>>>(Wsrc, Wdst, al, ar, gb, hb, wl, wr, btot);
    k_transw<<<dim3((R_REL * D * D + 255) / 256), dim3(256), 0, stream>>>(Wsrc, Wt);
    k_scores_cast<<<dim3(N_NODES / 8), dim3(256), 0, stream>>>(x, wl, wr, xb, el, er);
    k_gemm<<<dim3((N_NODES + 255) / 256, R_REL), dim3(512), 0, stream>>>(xb, Wt, hsb);
    k_scatter<<<dim3((E_EDGES + 255) / 256, R_REL), dim3(256), 0, stream>>>(esrc, edst, cnt, eidx);
    k_agg<<<dim3((N_NODES + 3) / 4), dim3(256), 0, stream>>>(eidx, cnt, el, er, hsb, btot, out);
}

// Round 8
// 189.814 us; speedup vs baseline: 1.2141x; 1.0505x over previous
//
#include <hip/hip_runtime.h>
#include <hip/hip_bf16.h>

#define N_NODES 100000
#define R_REL 4
#define E_EDGES 160000
#define D 128
#define NEG_SLOPE 0.2f
#define CAP 32   // max edges per dst (all relations); Poisson(6.4): P(>32)*100K ~ 1e-7

typedef unsigned short u16x8 __attribute__((ext_vector_type(8)));
typedef unsigned short u16x4 __attribute__((ext_vector_type(4)));
typedef __bf16 bf16x8v __attribute__((ext_vector_type(8)));
typedef float f32x4 __attribute__((ext_vector_type(4)));

__device__ inline unsigned short f2bf(float f) {
    unsigned u = __float_as_uint(f);
    return (unsigned short)((u + 0x7FFFu + ((u >> 16) & 1u)) >> 16);
}
__device__ inline float bf2f(unsigned short h) {
    return __uint_as_float(((unsigned)h) << 16);
}

// wl[r,d] = sum_e W_src[r,d,e]*attn_l[r,e]; wr likewise; btot = sum_r gat_bias + h_bias
__global__ void k_prep(const float* __restrict__ Wsrc, const float* __restrict__ Wdst,
                       const float* __restrict__ al, const float* __restrict__ ar,
                       const float* __restrict__ gb, const float* __restrict__ hb,
                       float* __restrict__ wl, float* __restrict__ wr, float* __restrict__ btot) {
    int t = threadIdx.x;            // 512 threads
    int r = t >> 7, d = t & 127;
    const float* as = al + r * D;
    const float* ad = ar + r * D;
    const float* rs = Wsrc + (r * D + d) * D;
    const float* rd = Wdst + (r * D + d) * D;
    float s0 = 0.f, s1 = 0.f;
    for (int e = 0; e < D; e++) { s0 += rs[e] * as[e]; s1 += rd[e] * ad[e]; }
    wl[r * D + d] = s0; wr[r * D + d] = s1;
    if (t < D) {
        float b = hb[t];
        for (int r2 = 0; r2 < R_REL; r2++) b += gb[r2 * D + t];
        btot[t] = b;
    }
}

// Wt[r][e][k] = bf16(W_src[r][k][e])
__global__ void k_transw(const float* __restrict__ Wsrc, unsigned short* __restrict__ Wt) {
    int idx = blockIdx.x * 256 + threadIdx.x;
    if (idx >= R_REL * D * D) return;
    int r = idx >> 14; int rem = idx & 16383; int e = rem >> 7; int k = rem & 127;
    Wt[idx] = f2bf(Wsrc[(r * D + k) * D + e]);
}

// fused: coalesced read of x (wave covers 2 rows), emits xb (bf16 cast),
// el[r,n] = x[n]·wl[r], er[r,n] = x[n]·wr[r] via shuffle reduce
__global__ __launch_bounds__(256) void k_scores_cast(const float* __restrict__ x,
        const float* __restrict__ wl, const float* __restrict__ wr,
        unsigned short* __restrict__ xb, float* __restrict__ el, float* __restrict__ er) {
    __shared__ float swl[R_REL * D], swr[R_REL * D];
    int t = threadIdx.x;
    for (int i = t; i < R_REL * D; i += 256) { swl[i] = wl[i]; swr[i] = wr[i]; }
    __syncthreads();
    int wv = t >> 6, lane = t & 63;
    int half = lane >> 5, q = lane & 31;           // q: float4 index within row
    long n = (long)blockIdx.x * 8 + wv * 2 + half; // N divisible by 8 -> no tail
    float4 v = ((const float4*)(x + n * D))[q];
    u16x4 ov;
    ov[0] = f2bf(v.x); ov[1] = f2bf(v.y); ov[2] = f2bf(v.z); ov[3] = f2bf(v.w);
    *(u16x4*)(xb + n * D + q * 4) = ov;
    float accl[R_REL], accr[R_REL];
    #pragma unroll
    for (int r = 0; r < R_REL; r++) {
        float4 w = ((const float4*)(swl + r * D))[q];
        accl[r] = v.x * w.x + v.y * w.y + v.z * w.z + v.w * w.w;
        float4 u = ((const float4*)(swr + r * D))[q];
        accr[r] = v.x * u.x + v.y * u.y + v.z * u.z + v.w * u.w;
    }
    #pragma unroll
    for (int r = 0; r < R_REL; r++) {
        #pragma unroll
        for (int d = 16; d >= 1; d >>= 1) {
            accl[r] += __shfl_xor(accl[r], d);
            accr[r] += __shfl_xor(accr[r], d);
        }
    }
    if (q == 0) {
        #pragma unroll
        for (int r = 0; r < R_REL; r++) {
            el[r * N_NODES + n] = accl[r];
            er[r * N_NODES + n] = accr[r];
        }
    }
}

// hs[r][n][e] bf16 = x_bf16 @ W_src[r] via mfma_f32_16x16x32_bf16.
// One relation per blockIdx.y: stage W_r into LDS once, 256 rows x 8 waves,
// single barrier (validated round 7).
__global__ __launch_bounds__(512) void k_gemm(const unsigned short* __restrict__ xb,
                                              const unsigned short* __restrict__ Wt,
                                              unsigned short* __restrict__ hs) {
    __shared__ unsigned short B[D][D + 8];   // padded: 128 x 136 bf16
    int tid = threadIdx.x;
    int w = tid >> 6, l = tid & 63;
    int row16 = l & 15, kgrp = l >> 4;
    int r = blockIdx.y;
    int n0 = blockIdx.x * 256;
    // hoist A-fragments (global reads overlap the LDS staging below)
    bf16x8v a[2][4];
    int nr[2];
    #pragma unroll
    for (int rf = 0; rf < 2; rf++) {
        int nrow = n0 + w * 32 + rf * 16 + row16;
        nr[rf] = nrow;
        int nc = nrow < N_NODES ? nrow : N_NODES - 1;
        #pragma unroll
        for (int kf = 0; kf < 4; kf++)
            a[rf][kf] = *(const bf16x8v*)(xb + (long)nc * D + kf * 32 + kgrp * 8);
    }
    // stage W_r: 512 threads x 4 iters x 8 elems = 16384
    const unsigned short* Wr = Wt + r * D * D;
    #pragma unroll
    for (int it = 0; it < 4; it++) {
        int fi = (it * 512 + tid) * 8;
        *(u16x8*)(&B[fi >> 7][fi & 127]) = *(const u16x8*)(Wr + fi);
    }
    __syncthreads();
    f32x4 acc[2][8];
    #pragma unroll
    for (int rf = 0; rf < 2; rf++)
        #pragma unroll
        for (int et = 0; et < 8; et++) {
            acc[rf][et][0] = 0.f; acc[rf][et][1] = 0.f;
            acc[rf][et][2] = 0.f; acc[rf][et][3] = 0.f;
        }
    #pragma unroll
    for (int kf = 0; kf < 4; kf++) {
        #pragma unroll
        for (int et = 0; et < 8; et++) {
            bf16x8v av = *(const bf16x8v*)(&B[et * 16 + row16][kf * 32 + kgrp * 8]);
            acc[0][et] = __builtin_amdgcn_mfma_f32_16x16x32_bf16(av, a[0][kf], acc[0][et], 0, 0, 0);
            acc[1][et] = __builtin_amdgcn_mfma_f32_16x16x32_bf16(av, a[1][kf], acc[1][et], 0, 0, 0);
        }
    }
    #pragma unroll
    for (int rf = 0; rf < 2; rf++) {
        if (nr[rf] < N_NODES) {
            unsigned short* orow = hs + ((long)r * N_NODES + nr[rf]) * D;
            #pragma unroll
            for (int et = 0; et < 8; et++) {
                u16x4 o;
                o[0] = f2bf(acc[rf][et][0]); o[1] = f2bf(acc[rf][et][1]);
                o[2] = f2bf(acc[rf][et][2]); o[3] = f2bf(acc[rf][et][3]);
                *(u16x4*)(orow + et * 16 + kgrp * 4) = o;
            }
        }
    }
}

// per-edge pass: compute p = exp(leaky(el+er)) here (latency overlaps the
// atomic), one atomic, scatter {rowid, p} into dst bucket
__global__ void k_scatter(const int* __restrict__ esrc, const int* __restrict__ edst,
                          const float* __restrict__ el, const float* __restrict__ er,
                          unsigned* __restrict__ cnt, int2* __restrict__ eb) {
    int e = blockIdx.x * 256 + threadIdx.x;
    if (e >= E_EDGES) return;
    int r = blockIdx.y;
    int t = r * E_EDGES + e;
    int src = esrc[t], dst = edst[t];
    float lg = el[r * N_NODES + src] + er[r * N_NODES + dst];
    lg = lg > 0.f ? lg : NEG_SLOPE * lg;
    float p = __expf(lg);
    unsigned pos = atomicAdd(cnt + dst, 1u);
    if (pos < CAP) eb[dst * CAP + pos] = make_int2(r * N_NODES + src, __float_as_int(p));
}

// one wave per dst: denominators from lane payloads (width-32 butterflies,
// no gathers/exp here), then 4-slot gather-accumulate of hs rows
__global__ __launch_bounds__(256) void k_agg(const int2* __restrict__ eb,
                                             const unsigned* __restrict__ cnt,
                                             const unsigned short* __restrict__ hs,
                                             const float* __restrict__ btot,
                                             float* __restrict__ out) {
    int wv = threadIdx.x >> 6, lane = threadIdx.x & 63;
    int dst = blockIdx.x * 4 + wv;
    if (dst >= N_NODES) return;
    unsigned num = cnt[dst];
    if (num > CAP) num = CAP;
    int rowid = 0, r = 0;
    float p = 0.f;
    if (lane < num) {                            // num <= 32: lanes 0..31 only
        int2 m = eb[dst * CAP + lane];
        rowid = m.x;                             // rowid = r*N + src
        p = __int_as_float(m.y);
        r = (int)((unsigned)rowid / (unsigned)N_NODES);
    }
    // per-relation denominators: width-32 butterflies, full EXEC
    float denom[R_REL];
    #pragma unroll
    for (int rr = 0; rr < R_REL; rr++) {
        float v = (r == rr) ? p : 0.f;
        #pragma unroll
        for (int d = 1; d < 32; d <<= 1) v += __shfl_xor(v, d, 32);
        denom[rr] = v;                           // valid in lanes 0..31
    }
    float alpha = (lane < num) ? p / denom[r] : 0.f;
    // gather-accumulate: 4 slots x 16 lanes (16B per lane covers a 256B hs row).
    // UNIFORM trip count: every lane executes every __shfl at full EXEC
    // (shfl from an exited lane is undefined on CDNA — round-3/4 bug).
    int slot = lane >> 4, c16 = lane & 15;
    float acc[8] = {0.f, 0.f, 0.f, 0.f, 0.f, 0.f, 0.f, 0.f};
    unsigned iters = (num + 3) >> 2;
    for (unsigned i = 0; i < iters; i++) {
        unsigned q = slot + i * 4;
        int rid = __shfl(rowid, (int)q);
        float al = __shfl(alpha, (int)q);
        if (q < num) {
            u16x8 v = *(const u16x8*)(hs + (long)rid * D + c16 * 8);
            #pragma unroll
            for (int j = 0; j < 8; j++) acc[j] += al * bf2f(v[j]);
        }
    }
    #pragma unroll
    for (int j = 0; j < 8; j++) {
        acc[j] += __shfl_xor(acc[j], 16);
        acc[j] += __shfl_xor(acc[j], 32);
    }
    if (slot == 0) {
        const float4 b0 = *(const float4*)(btot + c16 * 8);
        const float4 b1 = *(const float4*)(btot + c16 * 8 + 4);
        float4 o0, o1;
        o0.x = acc[0] + b0.x; o0.y = acc[1] + b0.y; o0.z = acc[2] + b0.z; o0.w = acc[3] + b0.w;
        o1.x = acc[4] + b1.x; o1.y = acc[5] + b1.y; o1.z = acc[6] + b1.z; o1.w = acc[7] + b1.w;
        o0.x = o0.x > 0.f ? o0.x : 0.f; o0.y = o0.y > 0.f ? o0.y : 0.f;
        o0.z = o0.z > 0.f ? o0.z : 0.f; o0.w = o0.w > 0.f ? o0.w : 0.f;
        o1.x = o1.x > 0.f ? o1.x : 0.f; o1.y = o1.y > 0.f ? o1.y : 0.f;
        o1.z = o1.z > 0.f ? o1.z : 0.f; o1.w = o1.w > 0.f ? o1.w : 0.f;
        *(float4*)(out + (long)dst * D + c16 * 8) = o0;
        *(float4*)(out + (long)dst * D + c16 * 8 + 4) = o1;
    }
}

extern "C" void kernel_launch(void* const* d_in, const int* in_sizes, int n_in,
                              void* d_out, int out_size, void* d_ws, size_t ws_size,
                              hipStream_t stream) {
    const float* x    = (const float*)d_in[0];
    const int*   esrc = (const int*)d_in[1];
    const int*   edst = (const int*)d_in[2];
    const float* Wsrc = (const float*)d_in[3];
    const float* Wdst = (const float*)d_in[4];
    const float* al   = (const float*)d_in[5];
    const float* ar   = (const float*)d_in[6];
    const float* gb   = (const float*)d_in[7];
    const float* hb   = (const float*)d_in[8];
    float* out = (float*)d_out;

    char* ws = (char*)d_ws;
    size_t o = 0;
    auto alloc = [&](size_t bytes) -> char* {
        char* r = ws + o; o += (bytes + 255) & ~(size_t)255; return r;
    };
    unsigned short* xb  = (unsigned short*)alloc((size_t)N_NODES * D * 2);   // 25.6 MB
    unsigned short* hsb = (unsigned short*)alloc((size_t)R_REL * N_NODES * D * 2);
    unsigned short* Wt  = (unsigned short*)alloc((size_t)R_REL * D * D * 2);
    float* el   = (float*)alloc((size_t)R_REL * N_NODES * 4);
    float* er   = (float*)alloc((size_t)R_REL * N_NODES * 4);
    float* wl   = (float*)alloc(R_REL * D * 4);
    float* wr   = (float*)alloc(R_REL * D * 4);
    float* btot = (float*)alloc(D * 4);
    unsigned* cnt = (unsigned*)alloc((size_t)N_NODES * 4);
    // eb (int2, 100K*32*8B = 25.6 MB) aliases xb (25.6 MB): xb is dead after
    // k_gemm, and k_scatter/k_agg are stream-ordered after k_gemm.
    int2* eb = (int2*)xb;

    hipMemsetAsync(cnt, 0, (size_t)N_NODES * 4, stream);
    k_prep<<<dim3(1), dim3(512), 0, stream>>>(Wsrc, Wdst, al, ar, gb, hb, wl, wr, btot);
    k_transw<<<dim3((R_REL * D * D + 255) / 256), dim3(256), 0, stream>>>(Wsrc, Wt);
    k_scores_cast<<<dim3(N_NODES / 8), dim3(256), 0, stream>>>(x, wl, wr, xb, el, er);
    k_gemm<<<dim3((N_NODES + 255) / 256, R_REL), dim3(512), 0, stream>>>(xb, Wt, hsb);
    k_scatter<<<dim3((E_EDGES + 255) / 256, R_REL), dim3(256), 0, stream>>>(esrc, edst, el, er, cnt, eb);
    k_agg<<<dim3((N_NODES + 3) / 4), dim3(256), 0, stream>>>(eb, cnt, hsb, btot, out);
}

// Round 9
// 174.322 us; speedup vs baseline: 1.3219x; 1.0889x over previous
//
#include <hip/hip_runtime.h>
#include <hip/hip_bf16.h>

#define N_NODES 100000
#define R_REL 4
#define E_EDGES 160000
#define D 128
#define NEG_SLOPE 0.2f
#define CAP 32   // max edges per dst (all relations); Poisson(6.4): P(>32)*100K ~ 1e-7

typedef unsigned short u16x8 __attribute__((ext_vector_type(8)));
typedef unsigned short u16x4 __attribute__((ext_vector_type(4)));
typedef __bf16 bf16x8v __attribute__((ext_vector_type(8)));
typedef float f32x4 __attribute__((ext_vector_type(4)));

__device__ inline unsigned short f2bf(float f) {
    unsigned u = __float_as_uint(f);
    return (unsigned short)((u + 0x7FFFu + ((u >> 16) & 1u)) >> 16);
}
__device__ inline float bf2f(unsigned short h) {
    return __uint_as_float(((unsigned)h) << 16);
}

// fused setup: block 0 = prep (wl/wr/btot), blocks 1-32 = W transpose+cast,
// blocks 33..228 = zero cnt. Saves two dispatches.
__global__ __launch_bounds__(512) void k_prep2(const float* __restrict__ Wsrc,
        const float* __restrict__ Wdst, const float* __restrict__ al,
        const float* __restrict__ ar, const float* __restrict__ gb,
        const float* __restrict__ hb, float* __restrict__ wl,
        float* __restrict__ wr, float* __restrict__ btot,
        unsigned short* __restrict__ Wt, unsigned* __restrict__ cnt) {
    int b = blockIdx.x, t = threadIdx.x;
    if (b == 0) {
        int r = t >> 7, d = t & 127;
        const float* as = al + r * D;
        const float* ad = ar + r * D;
        const float* rs = Wsrc + (r * D + d) * D;
        const float* rd = Wdst + (r * D + d) * D;
        float s0 = 0.f, s1 = 0.f;
        for (int e = 0; e < D; e++) { s0 += rs[e] * as[e]; s1 += rd[e] * ad[e]; }
        wl[r * D + d] = s0; wr[r * D + d] = s1;
        if (t < D) {
            float bb = hb[t];
            for (int r2 = 0; r2 < R_REL; r2++) bb += gb[r2 * D + t];
            btot[t] = bb;
        }
    } else if (b <= 32) {
        int base = (b - 1) * 2048 + t;
        #pragma unroll
        for (int i = 0; i < 4; i++) {
            int idx = base + i * 512;
            int r = idx >> 14; int rem = idx & 16383; int e = rem >> 7; int k = rem & 127;
            Wt[idx] = f2bf(Wsrc[(r * D + k) * D + e]);
        }
    } else {
        int i = (b - 33) * 512 + t;
        if (i < N_NODES) cnt[i] = 0u;
    }
}

// fused: coalesced read of x (wave covers 2 rows), emits xb (bf16 cast),
// el[r,n] = x[n]·wl[r], er[r,n] = x[n]·wr[r] via shuffle reduce
__global__ __launch_bounds__(256) void k_scores_cast(const float* __restrict__ x,
        const float* __restrict__ wl, const float* __restrict__ wr,
        unsigned short* __restrict__ xb, float* __restrict__ el, float* __restrict__ er) {
    __shared__ float swl[R_REL * D], swr[R_REL * D];
    int t = threadIdx.x;
    for (int i = t; i < R_REL * D; i += 256) { swl[i] = wl[i]; swr[i] = wr[i]; }
    __syncthreads();
    int wv = t >> 6, lane = t & 63;
    int half = lane >> 5, q = lane & 31;           // q: float4 index within row
    long n = (long)blockIdx.x * 8 + wv * 2 + half; // N divisible by 8 -> no tail
    float4 v = ((const float4*)(x + n * D))[q];
    u16x4 ov;
    ov[0] = f2bf(v.x); ov[1] = f2bf(v.y); ov[2] = f2bf(v.z); ov[3] = f2bf(v.w);
    *(u16x4*)(xb + n * D + q * 4) = ov;
    float accl[R_REL], accr[R_REL];
    #pragma unroll
    for (int r = 0; r < R_REL; r++) {
        float4 w = ((const float4*)(swl + r * D))[q];
        accl[r] = v.x * w.x + v.y * w.y + v.z * w.z + v.w * w.w;
        float4 u = ((const float4*)(swr + r * D))[q];
        accr[r] = v.x * u.x + v.y * u.y + v.z * u.z + v.w * u.w;
    }
    #pragma unroll
    for (int r = 0; r < R_REL; r++) {
        #pragma unroll
        for (int d = 16; d >= 1; d >>= 1) {
            accl[r] += __shfl_xor(accl[r], d);
            accr[r] += __shfl_xor(accr[r], d);
        }
    }
    if (q == 0) {
        #pragma unroll
        for (int r = 0; r < R_REL; r++) {
            el[r * N_NODES + n] = accl[r];
            er[r * N_NODES + n] = accr[r];
        }
    }
}

// hs[r][n][e] bf16 = x_bf16 @ W_src[r] via mfma_f32_16x16x32_bf16.
// One relation per blockIdx.y: stage W_r into LDS once, 256 rows x 8 waves,
// single barrier (validated round 7).
__global__ __launch_bounds__(512) void k_gemm(const unsigned short* __restrict__ xb,
                                              const unsigned short* __restrict__ Wt,
                                              unsigned short* __restrict__ hs) {
    __shared__ unsigned short B[D][D + 8];   // padded: 128 x 136 bf16
    int tid = threadIdx.x;
    int w = tid >> 6, l = tid & 63;
    int row16 = l & 15, kgrp = l >> 4;
    int r = blockIdx.y;
    int n0 = blockIdx.x * 256;
    // hoist A-fragments (global reads overlap the LDS staging below)
    bf16x8v a[2][4];
    int nr[2];
    #pragma unroll
    for (int rf = 0; rf < 2; rf++) {
        int nrow = n0 + w * 32 + rf * 16 + row16;
        nr[rf] = nrow;
        int nc = nrow < N_NODES ? nrow : N_NODES - 1;
        #pragma unroll
        for (int kf = 0; kf < 4; kf++)
            a[rf][kf] = *(const bf16x8v*)(xb + (long)nc * D + kf * 32 + kgrp * 8);
    }
    // stage W_r: 512 threads x 4 iters x 8 elems = 16384
    const unsigned short* Wr = Wt + r * D * D;
    #pragma unroll
    for (int it = 0; it < 4; it++) {
        int fi = (it * 512 + tid) * 8;
        *(u16x8*)(&B[fi >> 7][fi & 127]) = *(const u16x8*)(Wr + fi);
    }
    __syncthreads();
    f32x4 acc[2][8];
    #pragma unroll
    for (int rf = 0; rf < 2; rf++)
        #pragma unroll
        for (int et = 0; et < 8; et++) {
            acc[rf][et][0] = 0.f; acc[rf][et][1] = 0.f;
            acc[rf][et][2] = 0.f; acc[rf][et][3] = 0.f;
        }
    #pragma unroll
    for (int kf = 0; kf < 4; kf++) {
        #pragma unroll
        for (int et = 0; et < 8; et++) {
            bf16x8v av = *(const bf16x8v*)(&B[et * 16 + row16][kf * 32 + kgrp * 8]);
            acc[0][et] = __builtin_amdgcn_mfma_f32_16x16x32_bf16(av, a[0][kf], acc[0][et], 0, 0, 0);
            acc[1][et] = __builtin_amdgcn_mfma_f32_16x16x32_bf16(av, a[1][kf], acc[1][et], 0, 0, 0);
        }
    }
    #pragma unroll
    for (int rf = 0; rf < 2; rf++) {
        if (nr[rf] < N_NODES) {
            unsigned short* orow = hs + ((long)r * N_NODES + nr[rf]) * D;
            #pragma unroll
            for (int et = 0; et < 8; et++) {
                u16x4 o;
                o[0] = f2bf(acc[rf][et][0]); o[1] = f2bf(acc[rf][et][1]);
                o[2] = f2bf(acc[rf][et][2]); o[3] = f2bf(acc[rf][et][3]);
                *(u16x4*)(orow + et * 16 + kgrp * 4) = o;
            }
        }
    }
}

// per-edge pass: compute p = exp(leaky(el+er)) here (latency overlaps the
// atomic), one atomic, scatter {rowid, p} into dst bucket
__global__ void k_scatter(const int* __restrict__ esrc, const int* __restrict__ edst,
                          const float* __restrict__ el, const float* __restrict__ er,
                          unsigned* __restrict__ cnt, int2* __restrict__ eb) {
    int e = blockIdx.x * 256 + threadIdx.x;
    if (e >= E_EDGES) return;
    int r = blockIdx.y;
    int t = r * E_EDGES + e;
    int src = esrc[t], dst = edst[t];
    float lg = el[r * N_NODES + src] + er[r * N_NODES + dst];
    lg = lg > 0.f ? lg : NEG_SLOPE * lg;
    float p = __expf(lg);
    unsigned pos = atomicAdd(cnt + dst, 1u);
    if (pos < CAP) eb[dst * CAP + pos] = make_int2(r * N_NODES + src, __float_as_int(p));
}

// TWO dsts per wave: lanes 0-31 own dstA, 32-63 own dstB (CAP=32 fits a half).
// Width-32 denominator butterflies compute both dsts at once; epilogue serves
// both halves; gather loop keeps 4 edges in flight per wave (2 per dst).
__global__ __launch_bounds__(256) void k_agg(const int2* __restrict__ eb,
                                             const unsigned* __restrict__ cnt,
                                             const unsigned short* __restrict__ hs,
                                             const float* __restrict__ btot,
                                             float* __restrict__ out) {
    int wv = threadIdx.x >> 6, lane = threadIdx.x & 63;
    int half = lane >> 5, l32 = lane & 31;
    int dst = blockIdx.x * 8 + wv * 2 + half;    // N % 8 == 0 -> always valid
    unsigned num = cnt[dst];
    if (num > CAP) num = CAP;
    int rowid = 0, r = 0;
    float p = 0.f;
    if (l32 < num) {
        int2 m = eb[dst * CAP + l32];
        rowid = m.x;                             // rowid = r*N + src
        p = __int_as_float(m.y);
        r = (int)((unsigned)rowid / (unsigned)N_NODES);
    }
    // per-relation denominators: width-32 butterflies (stay within half), full EXEC
    float denom[R_REL];
    #pragma unroll
    for (int rr = 0; rr < R_REL; rr++) {
        float v = (r == rr) ? p : 0.f;
        #pragma unroll
        for (int d = 1; d < 32; d <<= 1) v += __shfl_xor(v, d, 32);
        denom[rr] = v;
    }
    float alpha = (l32 < num) ? p / denom[r] : 0.f;
    // gather-accumulate: per half, 2 slots x 16 lanes (16B/lane covers 256B row).
    // UNIFORM trip count across the wave; all shfl at full EXEC with q<=31
    // (shfl from an exited lane is undefined on CDNA — round-3/4 bug).
    int slot2 = l32 >> 4, c16 = lane & 15;
    float acc[8] = {0.f, 0.f, 0.f, 0.f, 0.f, 0.f, 0.f, 0.f};
    unsigned numo = __shfl_xor(num, 32);
    unsigned numMax = num > numo ? num : numo;
    unsigned iters = (numMax + 1) >> 1;
    for (unsigned i = 0; i < iters; i++) {
        unsigned q = slot2 + i * 2;              // q <= 31
        int src = half * 32 + (int)q;
        int rid = __shfl(rowid, src);
        float al = __shfl(alpha, src);
        if (q < num) {
            u16x8 v = *(const u16x8*)(hs + (long)rid * D + c16 * 8);
            #pragma unroll
            for (int j = 0; j < 8; j++) acc[j] += al * bf2f(v[j]);
        }
    }
    // reduce across the 2 slots within each half (xor 16 stays in-half)
    #pragma unroll
    for (int j = 0; j < 8; j++) acc[j] += __shfl_xor(acc[j], 16);
    if (slot2 == 0) {
        const float4 b0 = *(const float4*)(btot + c16 * 8);
        const float4 b1 = *(const float4*)(btot + c16 * 8 + 4);
        float4 o0, o1;
        o0.x = acc[0] + b0.x; o0.y = acc[1] + b0.y; o0.z = acc[2] + b0.z; o0.w = acc[3] + b0.w;
        o1.x = acc[4] + b1.x; o1.y = acc[5] + b1.y; o1.z = acc[6] + b1.z; o1.w = acc[7] + b1.w;
        o0.x = o0.x > 0.f ? o0.x : 0.f; o0.y = o0.y > 0.f ? o0.y : 0.f;
        o0.z = o0.z > 0.f ? o0.z : 0.f; o0.w = o0.w > 0.f ? o0.w : 0.f;
        o1.x = o1.x > 0.f ? o1.x : 0.f; o1.y = o1.y > 0.f ? o1.y : 0.f;
        o1.z = o1.z > 0.f ? o1.z : 0.f; o1.w = o1.w > 0.f ? o1.w : 0.f;
        *(float4*)(out + (long)dst * D + c16 * 8) = o0;
        *(float4*)(out + (long)dst * D + c16 * 8 + 4) = o1;
    }
}

extern "C" void kernel_launch(void* const* d_in, const int* in_sizes, int n_in,
                              void* d_out, int out_size, void* d_ws, size_t ws_size,
                              hipStream_t stream) {
    const float* x    = (const float*)d_in[0];
    const int*   esrc = (const int*)d_in[1];
    const int*   edst = (const int*)d_in[2];
    const float* Wsrc = (const float*)d_in[3];
    const float* Wdst = (const float*)d_in[4];
    const float* al   = (const float*)d_in[5];
    const float* ar   = (const float*)d_in[6];
    const float* gb   = (const float*)d_in[7];
    const float* hb   = (const float*)d_in[8];
    float* out = (float*)d_out;

    char* ws = (char*)d_ws;
    size_t o = 0;
    auto alloc = [&](size_t bytes) -> char* {
        char* r = ws + o; o += (bytes + 255) & ~(size_t)255; return r;
    };
    unsigned short* xb  = (unsigned short*)alloc((size_t)N_NODES * D * 2);   // 25.6 MB
    unsigned short* hsb = (unsigned short*)alloc((size_t)R_REL * N_NODES * D * 2);
    unsigned short* Wt  = (unsigned short*)alloc((size_t)R_REL * D * D * 2);
    float* el   = (float*)alloc((size_t)R_REL * N_NODES * 4);
    float* er   = (float*)alloc((size_t)R_REL * N_NODES * 4);
    float* wl   = (float*)alloc(R_REL * D * 4);
    float* wr   = (float*)alloc(R_REL * D * 4);
    float* btot = (float*)alloc(D * 4);
    unsigned* cnt = (unsigned*)alloc((size_t)N_NODES * 4);
    // eb (int2, 100K*32*8B = 25.6 MB) aliases xb (25.6 MB): xb is dead after
    // k_gemm, and k_scatter/k_agg are stream-ordered after k_gemm.
    int2* eb = (int2*)xb;

    int zblocks = (N_NODES + 511) / 512;                 // 196
    k_prep2<<<dim3(33 + zblocks), dim3(512), 0, stream>>>(Wsrc, Wdst, al, ar, gb, hb,
                                                          wl, wr, btot, Wt, cnt);
    k_scores_cast<<<dim3(N_NODES / 8), dim3(256), 0, stream>>>(x, wl, wr, xb, el, er);
    k_gemm<<<dim3((N_NODES + 255) / 256, R_REL), dim3(512), 0, stream>>>(xb, Wt, hsb);
    k_scatter<<<dim3((E_EDGES + 255) / 256, R_REL), dim3(256), 0, stream>>>(esrc, edst, el, er, cnt, eb);
    k_agg<<<dim3(N_NODES / 8), dim3(256), 0, stream>>>(eb, cnt, hsb, btot, out);
}

// Round 10
// 156.807 us; speedup vs baseline: 1.4696x; 1.1117x over previous
//
#include <hip/hip_runtime.h>
#include <hip/hip_bf16.h>

#define N_NODES 100000
#define R_REL 4
#define E_EDGES 160000
#define D 128
#define NEG_SLOPE 0.2f
#define CAP 32   // max edges per dst (all relations); Poisson(6.4): P(>32)*100K ~ 1e-10
#define GB 391   // gemm blocks per relation  = ceil(N/256)
#define SB 313   // scatter blocks per relation = ceil(E/512)

typedef unsigned short u16x8 __attribute__((ext_vector_type(8)));
typedef unsigned short u16x4 __attribute__((ext_vector_type(4)));
typedef __bf16 bf16x8v __attribute__((ext_vector_type(8)));
typedef float f32x4 __attribute__((ext_vector_type(4)));

__device__ inline unsigned short f2bf(float f) {
    unsigned u = __float_as_uint(f);
    return (unsigned short)((u + 0x7FFFu + ((u >> 16) & 1u)) >> 16);
}
__device__ inline float bf2f(unsigned short h) {
    return __uint_as_float(((unsigned)h) << 16);
}

// fused setup: block 0 = prep (wl/wr/btot), blocks 1-32 = W transpose+cast,
// blocks 33..228 = zero cnt.
__global__ __launch_bounds__(512) void k_prep2(const float* __restrict__ Wsrc,
        const float* __restrict__ Wdst, const float* __restrict__ al,
        const float* __restrict__ ar, const float* __restrict__ gb,
        const float* __restrict__ hb, float* __restrict__ wl,
        float* __restrict__ wr, float* __restrict__ btot,
        unsigned short* __restrict__ Wt, unsigned* __restrict__ cnt) {
    int b = blockIdx.x, t = threadIdx.x;
    if (b == 0) {
        int r = t >> 7, d = t & 127;
        const float* as = al + r * D;
        const float* ad = ar + r * D;
        const float* rs = Wsrc + (r * D + d) * D;
        const float* rd = Wdst + (r * D + d) * D;
        float s0 = 0.f, s1 = 0.f;
        for (int e = 0; e < D; e++) { s0 += rs[e] * as[e]; s1 += rd[e] * ad[e]; }
        wl[r * D + d] = s0; wr[r * D + d] = s1;
        if (t < D) {
            float bb = hb[t];
            for (int r2 = 0; r2 < R_REL; r2++) bb += gb[r2 * D + t];
            btot[t] = bb;
        }
    } else if (b <= 32) {
        int base = (b - 1) * 2048 + t;
        #pragma unroll
        for (int i = 0; i < 4; i++) {
            int idx = base + i * 512;
            int r = idx >> 14; int rem = idx & 16383; int e = rem >> 7; int k = rem & 127;
            Wt[idx] = f2bf(Wsrc[(r * D + k) * D + e]);
        }
    } else {
        int i = (b - 33) * 512 + t;
        if (i < N_NODES) cnt[i] = 0u;
    }
}

// fused: coalesced read of x (wave covers 2 rows), emits xb (bf16 cast),
// el[r,n] = x[n]·wl[r], er[r,n] = x[n]·wr[r] via shuffle reduce
__global__ __launch_bounds__(256) void k_scores_cast(const float* __restrict__ x,
        const float* __restrict__ wl, const float* __restrict__ wr,
        unsigned short* __restrict__ xb, float* __restrict__ el, float* __restrict__ er) {
    __shared__ float swl[R_REL * D], swr[R_REL * D];
    int t = threadIdx.x;
    for (int i = t; i < R_REL * D; i += 256) { swl[i] = wl[i]; swr[i] = wr[i]; }
    __syncthreads();
    int wv = t >> 6, lane = t & 63;
    int half = lane >> 5, q = lane & 31;           // q: float4 index within row
    long n = (long)blockIdx.x * 8 + wv * 2 + half; // N divisible by 8 -> no tail
    float4 v = ((const float4*)(x + n * D))[q];
    u16x4 ov;
    ov[0] = f2bf(v.x); ov[1] = f2bf(v.y); ov[2] = f2bf(v.z); ov[3] = f2bf(v.w);
    *(u16x4*)(xb + n * D + q * 4) = ov;
    float accl[R_REL], accr[R_REL];
    #pragma unroll
    for (int r = 0; r < R_REL; r++) {
        float4 w = ((const float4*)(swl + r * D))[q];
        accl[r] = v.x * w.x + v.y * w.y + v.z * w.z + v.w * w.w;
        float4 u = ((const float4*)(swr + r * D))[q];
        accr[r] = v.x * u.x + v.y * u.y + v.z * u.z + v.w * u.w;
    }
    #pragma unroll
    for (int r = 0; r < R_REL; r++) {
        #pragma unroll
        for (int d = 16; d >= 1; d >>= 1) {
            accl[r] += __shfl_xor(accl[r], d);
            accr[r] += __shfl_xor(accr[r], d);
        }
    }
    if (q == 0) {
        #pragma unroll
        for (int r = 0; r < R_REL; r++) {
            el[r * N_NODES + n] = accl[r];
            er[r * N_NODES + n] = accr[r];
        }
    }
}

// GEMM body (validated r7/r9): one relation, 256 rows, W_r staged once, 1 barrier
__device__ __forceinline__ void gemm_body(int bx, int r, int tid,
        const unsigned short* __restrict__ xb, const unsigned short* __restrict__ Wt,
        unsigned short* __restrict__ hs, unsigned short (*B)[D + 8]) {
    int w = tid >> 6, l = tid & 63;
    int row16 = l & 15, kgrp = l >> 4;
    int n0 = bx * 256;
    bf16x8v a[2][4];
    int nr[2];
    #pragma unroll
    for (int rf = 0; rf < 2; rf++) {
        int nrow = n0 + w * 32 + rf * 16 + row16;
        nr[rf] = nrow;
        int nc = nrow < N_NODES ? nrow : N_NODES - 1;
        #pragma unroll
        for (int kf = 0; kf < 4; kf++)
            a[rf][kf] = *(const bf16x8v*)(xb + (long)nc * D + kf * 32 + kgrp * 8);
    }
    const unsigned short* Wr = Wt + r * D * D;
    #pragma unroll
    for (int it = 0; it < 4; it++) {
        int fi = (it * 512 + tid) * 8;
        *(u16x8*)(&B[fi >> 7][fi & 127]) = *(const u16x8*)(Wr + fi);
    }
    __syncthreads();
    f32x4 acc[2][8];
    #pragma unroll
    for (int rf = 0; rf < 2; rf++)
        #pragma unroll
        for (int et = 0; et < 8; et++) {
            acc[rf][et][0] = 0.f; acc[rf][et][1] = 0.f;
            acc[rf][et][2] = 0.f; acc[rf][et][3] = 0.f;
        }
    #pragma unroll
    for (int kf = 0; kf < 4; kf++) {
        #pragma unroll
        for (int et = 0; et < 8; et++) {
            bf16x8v av = *(const bf16x8v*)(&B[et * 16 + row16][kf * 32 + kgrp * 8]);
            acc[0][et] = __builtin_amdgcn_mfma_f32_16x16x32_bf16(av, a[0][kf], acc[0][et], 0, 0, 0);
            acc[1][et] = __builtin_amdgcn_mfma_f32_16x16x32_bf16(av, a[1][kf], acc[1][et], 0, 0, 0);
        }
    }
    #pragma unroll
    for (int rf = 0; rf < 2; rf++) {
        if (nr[rf] < N_NODES) {
            unsigned short* orow = hs + ((long)r * N_NODES + nr[rf]) * D;
            #pragma unroll
            for (int et = 0; et < 8; et++) {
                u16x4 o;
                o[0] = f2bf(acc[rf][et][0]); o[1] = f2bf(acc[rf][et][1]);
                o[2] = f2bf(acc[rf][et][2]); o[3] = f2bf(acc[rf][et][3]);
                *(u16x4*)(orow + et * 16 + kgrp * 4) = o;
            }
        }
    }
}

__device__ __forceinline__ void scatter_edge(int e, int r,
        const int* __restrict__ esrc, const int* __restrict__ edst,
        const float* __restrict__ el, const float* __restrict__ er,
        unsigned* __restrict__ cnt, int2* __restrict__ eb) {
    int t = r * E_EDGES + e;
    int src = esrc[t], dst = edst[t];
    float lg = el[r * N_NODES + src] + er[r * N_NODES + dst];
    lg = lg > 0.f ? lg : NEG_SLOPE * lg;
    float p = __expf(lg);
    unsigned pos = atomicAdd(cnt + dst, 1u);
    if (pos < CAP) eb[dst * CAP + pos] = make_int2(r * N_NODES + src, __float_as_int(p));
}

// FUSED gemm+scatter: disjoint resources (MFMA/HBM vs atomic latency) overlap
// via block-role split. Requires eb separate from xb (no alias).
__global__ __launch_bounds__(512) void k_gemm_scatter(
        const unsigned short* __restrict__ xb, const unsigned short* __restrict__ Wt,
        unsigned short* __restrict__ hs, const int* __restrict__ esrc,
        const int* __restrict__ edst, const float* __restrict__ el,
        const float* __restrict__ er, unsigned* __restrict__ cnt,
        int2* __restrict__ eb) {
    __shared__ unsigned short B[D][D + 8];
    int bx = blockIdx.x, r = blockIdx.y, tid = threadIdx.x;
    if (bx < GB) {
        gemm_body(bx, r, tid, xb, Wt, hs, B);
    } else {
        int e = (bx - GB) * 512 + tid;
        if (e < E_EDGES) scatter_edge(e, r, esrc, edst, el, er, cnt, eb);
    }
}

// fallback split kernels (used when ws too small for separate eb)
__global__ __launch_bounds__(512) void k_gemm(const unsigned short* __restrict__ xb,
                                              const unsigned short* __restrict__ Wt,
                                              unsigned short* __restrict__ hs) {
    __shared__ unsigned short B[D][D + 8];
    gemm_body(blockIdx.x, blockIdx.y, threadIdx.x, xb, Wt, hs, B);
}

__global__ void k_scatter(const int* __restrict__ esrc, const int* __restrict__ edst,
                          const float* __restrict__ el, const float* __restrict__ er,
                          unsigned* __restrict__ cnt, int2* __restrict__ eb) {
    int e = blockIdx.x * 256 + threadIdx.x;
    if (e >= E_EDGES) return;
    scatter_edge(e, blockIdx.y, esrc, edst, el, er, cnt, eb);
}

// TWO dsts per wave: lanes 0-31 own dstA, 32-63 own dstB (validated round 9).
__global__ __launch_bounds__(256) void k_agg(const int2* __restrict__ eb,
                                             const unsigned* __restrict__ cnt,
                                             const unsigned short* __restrict__ hs,
                                             const float* __restrict__ btot,
                                             float* __restrict__ out) {
    int wv = threadIdx.x >> 6, lane = threadIdx.x & 63;
    int half = lane >> 5, l32 = lane & 31;
    int dst = blockIdx.x * 8 + wv * 2 + half;    // N % 8 == 0 -> always valid
    unsigned num = cnt[dst];
    if (num > CAP) num = CAP;
    int rowid = 0, r = 0;
    float p = 0.f;
    if (l32 < num) {
        int2 m = eb[dst * CAP + l32];
        rowid = m.x;                             // rowid = r*N + src
        p = __int_as_float(m.y);
        r = (int)((unsigned)rowid / (unsigned)N_NODES);
    }
    // per-relation denominators: width-32 butterflies (stay within half), full EXEC
    float denom[R_REL];
    #pragma unroll
    for (int rr = 0; rr < R_REL; rr++) {
        float v = (r == rr) ? p : 0.f;
        #pragma unroll
        for (int d = 1; d < 32; d <<= 1) v += __shfl_xor(v, d, 32);
        denom[rr] = v;
    }
    float alpha = (l32 < num) ? p / denom[r] : 0.f;
    // gather-accumulate: per half, 2 slots x 16 lanes; UNIFORM trip count,
    // all shfl at full EXEC (shfl from exited lane undefined — r3/4 bug).
    int slot2 = l32 >> 4, c16 = lane & 15;
    float acc[8] = {0.f, 0.f, 0.f, 0.f, 0.f, 0.f, 0.f, 0.f};
    unsigned numo = __shfl_xor(num, 32);
    unsigned numMax = num > numo ? num : numo;
    unsigned iters = (numMax + 1) >> 1;
    for (unsigned i = 0; i < iters; i++) {
        unsigned q = slot2 + i * 2;              // q <= 31
        int srcl = half * 32 + (int)q;
        int rid = __shfl(rowid, srcl);
        float al = __shfl(alpha, srcl);
        if (q < num) {
            u16x8 v = *(const u16x8*)(hs + (long)rid * D + c16 * 8);
            #pragma unroll
            for (int j = 0; j < 8; j++) acc[j] += al * bf2f(v[j]);
        }
    }
    #pragma unroll
    for (int j = 0; j < 8; j++) acc[j] += __shfl_xor(acc[j], 16);
    if (slot2 == 0) {
        const float4 b0 = *(const float4*)(btot + c16 * 8);
        const float4 b1 = *(const float4*)(btot + c16 * 8 + 4);
        float4 o0, o1;
        o0.x = acc[0] + b0.x; o0.y = acc[1] + b0.y; o0.z = acc[2] + b0.z; o0.w = acc[3] + b0.w;
        o1.x = acc[4] + b1.x; o1.y = acc[5] + b1.y; o1.z = acc[6] + b1.z; o1.w = acc[7] + b1.w;
        o0.x = o0.x > 0.f ? o0.x : 0.f; o0.y = o0.y > 0.f ? o0.y : 0.f;
        o0.z = o0.z > 0.f ? o0.z : 0.f; o0.w = o0.w > 0.f ? o0.w : 0.f;
        o1.x = o1.x > 0.f ? o1.x : 0.f; o1.y = o1.y > 0.f ? o1.y : 0.f;
        o1.z = o1.z > 0.f ? o1.z : 0.f; o1.w = o1.w > 0.f ? o1.w : 0.f;
        *(float4*)(out + (long)dst * D + c16 * 8) = o0;
        *(float4*)(out + (long)dst * D + c16 * 8 + 4) = o1;
    }
}

extern "C" void kernel_launch(void* const* d_in, const int* in_sizes, int n_in,
                              void* d_out, int out_size, void* d_ws, size_t ws_size,
                              hipStream_t stream) {
    const float* x    = (const float*)d_in[0];
    const int*   esrc = (const int*)d_in[1];
    const int*   edst = (const int*)d_in[2];
    const float* Wsrc = (const float*)d_in[3];
    const float* Wdst = (const float*)d_in[4];
    const float* al   = (const float*)d_in[5];
    const float* ar   = (const float*)d_in[6];
    const float* gb   = (const float*)d_in[7];
    const float* hb   = (const float*)d_in[8];
    float* out = (float*)d_out;

    char* ws = (char*)d_ws;
    size_t o = 0;
    auto alloc = [&](size_t bytes) -> char* {
        char* r = ws + o; o += (bytes + 255) & ~(size_t)255; return r;
    };
    unsigned short* xb  = (unsigned short*)alloc((size_t)N_NODES * D * 2);   // 25.6 MB
    unsigned short* hsb = (unsigned short*)alloc((size_t)R_REL * N_NODES * D * 2);
    unsigned short* Wt  = (unsigned short*)alloc((size_t)R_REL * D * D * 2);
    float* el   = (float*)alloc((size_t)R_REL * N_NODES * 4);
    float* er   = (float*)alloc((size_t)R_REL * N_NODES * 4);
    float* wl   = (float*)alloc(R_REL * D * 4);
    float* wr   = (float*)alloc(R_REL * D * 4);
    float* btot = (float*)alloc(D * 4);
    unsigned* cnt = (unsigned*)alloc((size_t)N_NODES * 4);
    size_t base_end = o;
    size_t eb_bytes = (size_t)N_NODES * CAP * 8;                 // 25.6 MB
    // Separate eb enables gemm+scatter fusion (eb must not alias xb, which the
    // gemm role reads concurrently). Deterministic runtime guard: fall back to
    // the r9-proven alias + sequential dispatches if ws is too small.
    bool fused = (base_end + eb_bytes) <= ws_size;
    int2* eb = fused ? (int2*)alloc(eb_bytes) : (int2*)xb;

    int zblocks = (N_NODES + 511) / 512;                 // 196
    k_prep2<<<dim3(33 + zblocks), dim3(512), 0, stream>>>(Wsrc, Wdst, al, ar, gb, hb,
                                                          wl, wr, btot, Wt, cnt);
    k_scores_cast<<<dim3(N_NODES / 8), dim3(256), 0, stream>>>(x, wl, wr, xb, el, er);
    if (fused) {
        k_gemm_scatter<<<dim3(GB + SB, R_REL), dim3(512), 0, stream>>>(
            xb, Wt, hsb, esrc, edst, el, er, cnt, eb);
    } else {
        k_gemm<<<dim3(GB, R_REL), dim3(512), 0, stream>>>(xb, Wt, hsb);
        k_scatter<<<dim3((E_EDGES + 255) / 256, R_REL), dim3(256), 0, stream>>>(
            esrc, edst, el, er, cnt, eb);
    }
    k_agg<<<dim3(N_NODES / 8), dim3(256), 0, stream>>>(eb, cnt, hsb, btot, out);
}